// Round 5
// baseline (197.307 us; speedup 1.0000x reference)
//
#include <hip/hip_runtime.h>
#include <math.h>

// ProductManifoldPhasorBlock — R5: 4-dispatch fusion (dispatch overhead ~13µs
// dominates; kernel-sum is ~30µs). Pipeline:
//  1) gemm1        : 5x (MLP1 GELU -> h bf16) + (V proj -> VT bf16), fp32 in-kernel cast
//  2) gemm2_phasor : 4x MLP2 (tanh*scale -> LDS) + phasor + PhiKT transpose
//  3) scan_fused   : per-(b,chunk,dhalf) state recompute (MFMA, fp32 acc) + retrieve
//  4) out_ln_gemm  : LayerNorm in A-staging + out proj + residual
// B=4, L=1024, D=256, K=64 (k2=128), 16 chunks of 64.

#define Bn 4
#define Ln 1024
#define BLn 4096

typedef __attribute__((ext_vector_type(8))) short bf16x8;
typedef __attribute__((ext_vector_type(4))) float f32x4;

__device__ inline ushort f2bf(float f) {
  union { float f; uint u; } x; x.f = f;
  uint r = x.u + 0x7fffu + ((x.u >> 16) & 1u);
  return (ushort)(r >> 16);
}
__device__ inline uint pk2(float a, float b) {
  return (uint)f2bf(a) | ((uint)f2bf(b) << 16);
}

// --------------------------------------------------- gemm1 (cast + MFMA)
// act 1: GELU -> bf16 Y[4096][256]; act 4: bf16 transposed -> VT[256][4096]
struct G1Prob { const float* X; const float* W; const float* bias; void* Y; int act; };
struct G1Args { G1Prob p[5]; };

__global__ __launch_bounds__(256) void gemm1(G1Args args) {
  const G1Prob p = args.p[blockIdx.z];
  __shared__ ushort As[64 * 40];
  __shared__ ushort Bs[64 * 40];
  const int tid = threadIdx.x;
  const int m0 = blockIdx.x * 64, n0 = blockIdx.y * 64;
  const int lane = tid & 63, wave = tid >> 6;
  const int wr = wave >> 1, wc = wave & 1;
  const int fr = lane & 15, quad = lane >> 4;
  f32x4 acc[2][2];
#pragma unroll
  for (int i = 0; i < 2; i++)
#pragma unroll
    for (int j = 0; j < 2; j++) acc[i][j] = (f32x4){0.f, 0.f, 0.f, 0.f};

  const int srow = tid >> 2, sch = (tid & 3) * 8;
  for (int k0 = 0; k0 < 256; k0 += 32) {
    float4 a0 = *(const float4*)(p.X + (size_t)(m0 + srow) * 256 + k0 + sch);
    float4 a1 = *(const float4*)(p.X + (size_t)(m0 + srow) * 256 + k0 + sch + 4);
    float4 b0 = *(const float4*)(p.W + (size_t)(n0 + srow) * 256 + k0 + sch);
    float4 b1 = *(const float4*)(p.W + (size_t)(n0 + srow) * 256 + k0 + sch + 4);
    uint4 pa = { pk2(a0.x, a0.y), pk2(a0.z, a0.w), pk2(a1.x, a1.y), pk2(a1.z, a1.w) };
    uint4 pb = { pk2(b0.x, b0.y), pk2(b0.z, b0.w), pk2(b1.x, b1.y), pk2(b1.z, b1.w) };
    *(uint4*)&As[srow * 40 + sch] = pa;
    *(uint4*)&Bs[srow * 40 + sch] = pb;
    __syncthreads();
    bf16x8 fa0 = *(const bf16x8*)&As[(wr * 32 + fr) * 40 + quad * 8];
    bf16x8 fa1 = *(const bf16x8*)&As[(wr * 32 + 16 + fr) * 40 + quad * 8];
    bf16x8 fb0 = *(const bf16x8*)&Bs[(wc * 32 + fr) * 40 + quad * 8];
    bf16x8 fb1 = *(const bf16x8*)&Bs[(wc * 32 + 16 + fr) * 40 + quad * 8];
    acc[0][0] = __builtin_amdgcn_mfma_f32_16x16x32_bf16(fa0, fb0, acc[0][0], 0, 0, 0);
    acc[0][1] = __builtin_amdgcn_mfma_f32_16x16x32_bf16(fa0, fb1, acc[0][1], 0, 0, 0);
    acc[1][0] = __builtin_amdgcn_mfma_f32_16x16x32_bf16(fa1, fb0, acc[1][0], 0, 0, 0);
    acc[1][1] = __builtin_amdgcn_mfma_f32_16x16x32_bf16(fa1, fb1, acc[1][1], 0, 0, 0);
    __syncthreads();
  }
#pragma unroll
  for (int i = 0; i < 2; i++)
#pragma unroll
    for (int j = 0; j < 2; j++) {
      int col = n0 + wc * 32 + j * 16 + fr;
      float bv = p.bias[col];
      if (p.act == 4) {
        int rowg0 = m0 + wr * 32 + i * 16 + quad * 4;
        ushort4 st;
        st.x = f2bf(acc[i][j][0] + bv);
        st.y = f2bf(acc[i][j][1] + bv);
        st.z = f2bf(acc[i][j][2] + bv);
        st.w = f2bf(acc[i][j][3] + bv);
        *(ushort4*)((ushort*)p.Y + (size_t)col * 4096 + rowg0) = st;
      } else {
#pragma unroll
        for (int r = 0; r < 4; r++) {
          int rowg = m0 + wr * 32 + i * 16 + quad * 4 + r;
          float o = acc[i][j][r] + bv;
          o = 0.5f * o * (1.0f + erff(o * 0.70710678118654752f));
          ((ushort*)p.Y)[(size_t)rowg * 256 + col] = f2bf(o);
        }
      }
    }
}

// ------------------------------------- gemm2 + phasor + PhiKT (fused)
struct P2Args { const ushort* h[4]; const float* w[4]; const float* bias[4];
                int Nreal[4]; float scale[4]; uint* PhiQ; uint* PhiK; uint* PhiKT; };

__global__ __launch_bounds__(256) void gemm2_phasor(P2Args a) {
  __shared__ ushort As[64 * 40];
  __shared__ ushort Bs[64 * 40];
  __shared__ float O[4][64][66];
  __shared__ ushort LK[64][130];
  const int tid = threadIdx.x;
  const int row0 = blockIdx.x * 64;
  const int b = row0 >> 10, lb0 = row0 & 1023;
  const int lane = tid & 63, wave = tid >> 6;
  const int wr = wave >> 1, wc = wave & 1;
  const int fr = lane & 15, quad = lane >> 4;
  const int srow = tid >> 2, sch = (tid & 3) * 8;

  for (int pi = 0; pi < 4; pi++) {
    const ushort* X = a.h[pi];
    const float* W = a.w[pi];
    const int Nr = a.Nreal[pi];
    f32x4 acc[2][2];
#pragma unroll
    for (int i = 0; i < 2; i++)
#pragma unroll
      for (int j = 0; j < 2; j++) acc[i][j] = (f32x4){0.f, 0.f, 0.f, 0.f};
    for (int k0 = 0; k0 < 256; k0 += 32) {
      uint4 pa = *(const uint4*)(X + (size_t)(row0 + srow) * 256 + k0 + sch);
      float4 b0 = {0.f,0.f,0.f,0.f}, b1 = {0.f,0.f,0.f,0.f};
      if (srow < Nr) {
        b0 = *(const float4*)(W + (size_t)srow * 256 + k0 + sch);
        b1 = *(const float4*)(W + (size_t)srow * 256 + k0 + sch + 4);
      }
      uint4 pb = { pk2(b0.x, b0.y), pk2(b0.z, b0.w), pk2(b1.x, b1.y), pk2(b1.z, b1.w) };
      *(uint4*)&As[srow * 40 + sch] = pa;
      *(uint4*)&Bs[srow * 40 + sch] = pb;
      __syncthreads();
      bf16x8 fa0 = *(const bf16x8*)&As[(wr * 32 + fr) * 40 + quad * 8];
      bf16x8 fa1 = *(const bf16x8*)&As[(wr * 32 + 16 + fr) * 40 + quad * 8];
      bf16x8 fb0 = *(const bf16x8*)&Bs[(wc * 32 + fr) * 40 + quad * 8];
      bf16x8 fb1 = *(const bf16x8*)&Bs[(wc * 32 + 16 + fr) * 40 + quad * 8];
      acc[0][0] = __builtin_amdgcn_mfma_f32_16x16x32_bf16(fa0, fb0, acc[0][0], 0, 0, 0);
      acc[0][1] = __builtin_amdgcn_mfma_f32_16x16x32_bf16(fa0, fb1, acc[0][1], 0, 0, 0);
      acc[1][0] = __builtin_amdgcn_mfma_f32_16x16x32_bf16(fa1, fb0, acc[1][0], 0, 0, 0);
      acc[1][1] = __builtin_amdgcn_mfma_f32_16x16x32_bf16(fa1, fb1, acc[1][1], 0, 0, 0);
      __syncthreads();
    }
    const float sc = a.scale[pi];
#pragma unroll
    for (int i = 0; i < 2; i++)
#pragma unroll
      for (int j = 0; j < 2; j++) {
        int col = wc * 32 + j * 16 + fr;
        float bv = (col < Nr) ? a.bias[pi][col] : 0.f;
#pragma unroll
        for (int r = 0; r < 4; r++) {
          int row = wr * 32 + i * 16 + quad * 4 + r;
          O[pi][row][col] = tanhf(acc[i][j][r] + bv) * sc;
        }
      }
  }
  __syncthreads();

  // phasor: per (row, k) build phasors, write PhiQ/PhiK, transpose PhiK -> PhiKT
#pragma unroll
  for (int it = 0; it < 16; it++) {
    int idx = tid + it * 256;          // 64 rows x 64 k
    int k = idx & 63, rl = idx >> 6;
    int row = row0 + rl;
    float kre, kim, qre, qim;
    if (k < 48) {
      float ka = O[0][rl][k], qa = O[1][rl][k];
      __sincosf(ka, &kim, &kre);
      __sincosf(qa, &qim, &qre);
    } else {
      int j2 = (k - 48) * 2;
      float av = O[2][rl][j2], bv = O[2][rl][j2 + 1];
      float rr = sqrtf(av * av + bv * bv);
      if (rr > 0.f) { float inv = (1.0f - rr) / rr; kre = av * inv; kim = bv * inv; }
      else          { kre = 1.0f; kim = 0.0f; }
      av = O[3][rl][j2]; bv = O[3][rl][j2 + 1];
      rr = sqrtf(av * av + bv * bv);
      if (rr > 0.f) { float inv = (1.0f - rr) / rr; qre = av * inv; qim = bv * inv; }
      else          { qre = 1.0f; qim = 0.0f; }
    }
    uint pk = pk2(kre, kim);
    uint pq = pk2(qre, qim);
    a.PhiK[(size_t)row * 64 + k] = pk;
    a.PhiQ[(size_t)row * 64 + k] = pq;
    *(uint*)&LK[rl][2 * k] = pk;
  }
  __syncthreads();
#pragma unroll
  for (int it = 0; it < 16; it++) {    // 128 k2-rows x 32 l-pairs = 4096
    int idx = tid + it * 256;
    int k2 = idx >> 5, lp = idx & 31;
    uint v = (uint)LK[lp * 2][k2] | ((uint)LK[lp * 2 + 1][k2] << 16);
    a.PhiKT[(size_t)b * 65536 + k2 * 512 + (lb0 >> 1) + lp] = v;
  }
}

// -------------------------------------------- scan (kv + prefix + retrieve)
// grid (bc = b*16+c : 64, dhalf : 2). Recompute state for chunks < c in fp32
// MFMA accumulators, LDS round-trip, then inter + masked intra as before.
__global__ __launch_bounds__(256) void scan_fused(const ushort* PhiQ, const ushort* PhiK,
                                                  const ushort* PhiKT, const ushort* VT,
                                                  float* R) {
  __shared__ ushort S_lds[128 * 144];   // [d_local][k2], stride 144 (288B, 16-aligned)
  __shared__ ushort Sl[64 * 72];
  const int bc = blockIdx.x;
  const int b = bc >> 4, c = bc & 15;
  const int d0 = blockIdx.y * 128;
  const int tid = threadIdx.x, lane = tid & 63, wave = tid >> 6;
  const int wr = wave >> 1, wc = wave & 1;
  const int fr = lane & 15, quad = lane >> 4;

  // 1) state S[d=128][k2=128] = sum over chunks cc<c of V_cc^T PhiK_cc
  f32x4 st[4][4];
#pragma unroll
  for (int i = 0; i < 4; i++)
#pragma unroll
    for (int j = 0; j < 4; j++) st[i][j] = (f32x4){0.f, 0.f, 0.f, 0.f};
  for (int cc = 0; cc < c; cc++) {
    const int colb = b * 1024 + cc * 64;
#pragma unroll
    for (int kk = 0; kk < 2; kk++) {
      bf16x8 av[4], bv[4];
#pragma unroll
      for (int i = 0; i < 4; i++)
        av[i] = *(const bf16x8*)(VT + (size_t)(d0 + wr * 64 + i * 16 + fr) * 4096 + colb + kk * 32 + quad * 8);
#pragma unroll
      for (int j = 0; j < 4; j++)
        bv[j] = *(const bf16x8*)(PhiKT + (size_t)b * 131072 + (size_t)(wc * 64 + j * 16 + fr) * 1024 + cc * 64 + kk * 32 + quad * 8);
#pragma unroll
      for (int i = 0; i < 4; i++)
#pragma unroll
        for (int j = 0; j < 4; j++)
          st[i][j] = __builtin_amdgcn_mfma_f32_16x16x32_bf16(av[i], bv[j], st[i][j], 0, 0, 0);
    }
  }
  // 2) state -> LDS bf16 (C-layout scatter; scalar b16 stores)
#pragma unroll
  for (int i = 0; i < 4; i++)
#pragma unroll
    for (int j = 0; j < 4; j++)
#pragma unroll
      for (int r = 0; r < 4; r++) {
        int dl = wr * 64 + i * 16 + quad * 4 + r;
        int k2 = wc * 64 + j * 16 + fr;
        S_lds[dl * 144 + k2] = f2bf(st[i][j][r]);
      }
  __syncthreads();

  // 3) retrieve
  const int wy = wave;
  const int g0 = b * 1024 + c * 64;
  bf16x8 aq[4][4];
#pragma unroll
  for (int i = 0; i < 4; i++)
#pragma unroll
    for (int kk = 0; kk < 4; kk++)
      aq[i][kk] = *(const bf16x8*)(PhiQ + (size_t)(g0 + i * 16 + fr) * 128 + kk * 32 + quad * 8);

  f32x4 acc[4][2];
#pragma unroll
  for (int i = 0; i < 4; i++)
#pragma unroll
    for (int j = 0; j < 2; j++) acc[i][j] = (f32x4){0.f, 0.f, 0.f, 0.f};

  // inter-chunk: PhiQ @ S^T (B-frags from S_lds)
#pragma unroll
  for (int kk = 0; kk < 4; kk++) {
    bf16x8 bb[2];
#pragma unroll
    for (int j = 0; j < 2; j++)
      bb[j] = *(const bf16x8*)&S_lds[(wy * 32 + j * 16 + fr) * 144 + kk * 32 + quad * 8];
#pragma unroll
    for (int i = 0; i < 4; i++)
#pragma unroll
      for (int j = 0; j < 2; j++)
        acc[i][j] = __builtin_amdgcn_mfma_f32_16x16x32_bf16(aq[i][kk], bb[j], acc[i][j], 0, 0, 0);
  }

  // intra-chunk scores (wave wy = 16-col strip), mask, -> Sl
  f32x4 sacc[4];
#pragma unroll
  for (int i = 0; i < 4; i++) sacc[i] = (f32x4){0.f, 0.f, 0.f, 0.f};
#pragma unroll
  for (int kk = 0; kk < 4; kk++) {
    bf16x8 bs = *(const bf16x8*)(PhiK + (size_t)(g0 + wy * 16 + fr) * 128 + kk * 32 + quad * 8);
#pragma unroll
    for (int i = 0; i < 4; i++)
      sacc[i] = __builtin_amdgcn_mfma_f32_16x16x32_bf16(aq[i][kk], bs, sacc[i], 0, 0, 0);
  }
#pragma unroll
  for (int i = 0; i < 4; i++)
#pragma unroll
    for (int r = 0; r < 4; r++) {
      int row = i * 16 + quad * 4 + r;
      int col = wy * 16 + fr;
      Sl[row * 72 + col] = (col <= row) ? f2bf(sacc[i][r]) : (ushort)0;
    }
  __syncthreads();

  // intra-chunk PV: tril(S) @ V
#pragma unroll
  for (int kk = 0; kk < 2; kk++) {
    bf16x8 as[4], bvv[2];
#pragma unroll
    for (int i = 0; i < 4; i++)
      as[i] = *(const bf16x8*)&Sl[(i * 16 + fr) * 72 + kk * 32 + quad * 8];
#pragma unroll
    for (int j = 0; j < 2; j++)
      bvv[j] = *(const bf16x8*)(VT + (size_t)(d0 + wy * 32 + j * 16 + fr) * 4096 + g0 + kk * 32 + quad * 8);
#pragma unroll
    for (int i = 0; i < 4; i++)
#pragma unroll
      for (int j = 0; j < 2; j++)
        acc[i][j] = __builtin_amdgcn_mfma_f32_16x16x32_bf16(as[i], bvv[j], acc[i][j], 0, 0, 0);
  }

#pragma unroll
  for (int i = 0; i < 4; i++)
#pragma unroll
    for (int j = 0; j < 2; j++)
#pragma unroll
      for (int r = 0; r < 4; r++) {
        int row = i * 16 + quad * 4 + r;
        int d = d0 + wy * 32 + j * 16 + fr;
        float scale = rsqrtf((float)((c * 64 + row + 1) * 64));
        R[(size_t)(g0 + row) * 256 + d] = acc[i][j][r] * scale;
      }
}

// ----------------------------------------- LayerNorm + out proj + residual
__global__ __launch_bounds__(256) void out_ln_gemm(const float* r, const float* g,
                                                   const float* bta, const float* W,
                                                   const float* ob, const float* x,
                                                   float* Y) {
  __shared__ ushort A_lds[64 * 272];   // [row][k 0..255], stride 272 (544B, 16-aligned)
  __shared__ ushort Bs[64 * 40];
  __shared__ float gs[256], bs2[256];
  const int tid = threadIdx.x;
  const int m0 = blockIdx.x * 64, n0 = blockIdx.y * 64;
  gs[tid] = g[tid];
  bs2[tid] = bta[tid];

  // phase 1: LayerNorm rows -> bf16 A_lds (4 threads per row)
  const int row_l = tid >> 2, seg = (tid & 3) * 64;
  const float* rr = r + (size_t)(m0 + row_l) * 256 + seg;
  float s = 0.f, sq = 0.f;
#pragma unroll
  for (int i = 0; i < 64; i += 4) {
    float4 v = *(const float4*)(rr + i);
    s += v.x + v.y + v.z + v.w;
    sq += v.x * v.x + v.y * v.y + v.z * v.z + v.w * v.w;
  }
  s += __shfl_xor(s, 1); sq += __shfl_xor(sq, 1);
  s += __shfl_xor(s, 2); sq += __shfl_xor(sq, 2);
  float mean = s * (1.0f / 256.0f);
  float var = fmaxf(sq * (1.0f / 256.0f) - mean * mean, 0.f);
  float rstd = rsqrtf(var + 1e-5f);
  __syncthreads();   // gs/bs2 ready
#pragma unroll
  for (int i = 0; i < 64; i += 4) {
    float4 v = *(const float4*)(rr + i);
    int k = seg + i;
    ushort4 st;
    st.x = f2bf((v.x - mean) * rstd * gs[k + 0] + bs2[k + 0]);
    st.y = f2bf((v.y - mean) * rstd * gs[k + 1] + bs2[k + 1]);
    st.z = f2bf((v.z - mean) * rstd * gs[k + 2] + bs2[k + 2]);
    st.w = f2bf((v.w - mean) * rstd * gs[k + 3] + bs2[k + 3]);
    *(ushort4*)&A_lds[row_l * 272 + k] = st;
  }
  __syncthreads();

  // phase 2: GEMM (A from A_lds, B staged fp32->bf16 per k0)
  const int lane = tid & 63, wave = tid >> 6;
  const int wr = wave >> 1, wc = wave & 1;
  const int fr = lane & 15, quad = lane >> 4;
  const int srow = tid >> 2, sch = (tid & 3) * 8;
  f32x4 acc[2][2];
#pragma unroll
  for (int i = 0; i < 2; i++)
#pragma unroll
    for (int j = 0; j < 2; j++) acc[i][j] = (f32x4){0.f, 0.f, 0.f, 0.f};
  for (int k0 = 0; k0 < 256; k0 += 32) {
    float4 b0 = *(const float4*)(W + (size_t)(n0 + srow) * 256 + k0 + sch);
    float4 b1 = *(const float4*)(W + (size_t)(n0 + srow) * 256 + k0 + sch + 4);
    uint4 pb = { pk2(b0.x, b0.y), pk2(b0.z, b0.w), pk2(b1.x, b1.y), pk2(b1.z, b1.w) };
    *(uint4*)&Bs[srow * 40 + sch] = pb;
    __syncthreads();
    bf16x8 fa0 = *(const bf16x8*)&A_lds[(wr * 32 + fr) * 272 + k0 + quad * 8];
    bf16x8 fa1 = *(const bf16x8*)&A_lds[(wr * 32 + 16 + fr) * 272 + k0 + quad * 8];
    bf16x8 fb0 = *(const bf16x8*)&Bs[(wc * 32 + fr) * 40 + quad * 8];
    bf16x8 fb1 = *(const bf16x8*)&Bs[(wc * 32 + 16 + fr) * 40 + quad * 8];
    acc[0][0] = __builtin_amdgcn_mfma_f32_16x16x32_bf16(fa0, fb0, acc[0][0], 0, 0, 0);
    acc[0][1] = __builtin_amdgcn_mfma_f32_16x16x32_bf16(fa0, fb1, acc[0][1], 0, 0, 0);
    acc[1][0] = __builtin_amdgcn_mfma_f32_16x16x32_bf16(fa1, fb0, acc[1][0], 0, 0, 0);
    acc[1][1] = __builtin_amdgcn_mfma_f32_16x16x32_bf16(fa1, fb1, acc[1][1], 0, 0, 0);
    __syncthreads();
  }
#pragma unroll
  for (int i = 0; i < 2; i++)
#pragma unroll
    for (int j = 0; j < 2; j++) {
      int col = n0 + wc * 32 + j * 16 + fr;
      float bv = ob[col];
#pragma unroll
      for (int r = 0; r < 4; r++) {
        int rowg = m0 + wr * 32 + i * 16 + quad * 4 + r;
        Y[(size_t)rowg * 256 + col] = acc[i][j][r] + bv + x[(size_t)rowg * 256 + col];
      }
    }
}

// ------------------------------------------------------------------- launch
extern "C" void kernel_launch(void* const* d_in, const int* in_sizes, int n_in,
                              void* d_out, int out_size, void* d_ws, size_t ws_size,
                              hipStream_t stream) {
  const float* x     = (const float*)d_in[0];
  const float* kp_w1 = (const float*)d_in[1];
  const float* kp_b1 = (const float*)d_in[2];
  const float* kp_w2 = (const float*)d_in[3];
  const float* kp_b2 = (const float*)d_in[4];
  const float* qp_w1 = (const float*)d_in[5];
  const float* qp_b1 = (const float*)d_in[6];
  const float* qp_w2 = (const float*)d_in[7];
  const float* qp_b2 = (const float*)d_in[8];
  const float* kh_w1 = (const float*)d_in[9];
  const float* kh_b1 = (const float*)d_in[10];
  const float* kh_w2 = (const float*)d_in[11];
  const float* kh_b2 = (const float*)d_in[12];
  const float* qh_w1 = (const float*)d_in[13];
  const float* qh_b1 = (const float*)d_in[14];
  const float* qh_w2 = (const float*)d_in[15];
  const float* qh_b2 = (const float*)d_in[16];
  const float* v_w   = (const float*)d_in[17];
  const float* v_b   = (const float*)d_in[18];
  const float* ln_g  = (const float*)d_in[19];
  const float* ln_b  = (const float*)d_in[20];
  const float* out_w = (const float*)d_in[21];
  const float* out_b = (const float*)d_in[22];

  char* ws = (char*)d_ws;
  const size_t MiB = 1024 * 1024;
  ushort* h0   = (ushort*)(ws + 0);           // [4096][256] bf16, 2 MiB each
  ushort* h1   = (ushort*)(ws + 2 * MiB);
  ushort* h2   = (ushort*)(ws + 4 * MiB);
  ushort* h3   = (ushort*)(ws + 6 * MiB);
  ushort* VT   = (ushort*)(ws + 8 * MiB);     // [256][4096] bf16, 2 MiB
  uint*   PhiQ = (uint*)(ws + 10 * MiB);      // [4096][64] packed re/im, 1 MiB
  uint*   PhiK = (uint*)(ws + 11 * MiB);      // 1 MiB
  uint*   PhiKT= (uint*)(ws + 12 * MiB);      // [4][128][512], 1 MiB
  float*  r    = (float*)(ws + 13 * MiB);     // [4096][256] fp32, 4 MiB

  // 1) first layers + V projection (fp32 inputs, in-kernel cast)
  G1Args g1;
  g1.p[0] = { x, kp_w1, kp_b1, h0, 1 };
  g1.p[1] = { x, qp_w1, qp_b1, h1, 1 };
  g1.p[2] = { x, kh_w1, kh_b1, h2, 1 };
  g1.p[3] = { x, qh_w1, qh_b1, h3, 1 };
  g1.p[4] = { x, v_w,   v_b,   VT, 4 };
  gemm1<<<dim3(64, 4, 5), 256, 0, stream>>>(g1);

  // 2) second layers + phasor + PhiKT
  const float PI_F = 3.14159265358979323846f;
  P2Args p2;
  p2.h[0] = h0; p2.h[1] = h1; p2.h[2] = h2; p2.h[3] = h3;
  p2.w[0] = kp_w2; p2.w[1] = qp_w2; p2.w[2] = kh_w2; p2.w[3] = qh_w2;
  p2.bias[0] = kp_b2; p2.bias[1] = qp_b2; p2.bias[2] = kh_b2; p2.bias[3] = qh_b2;
  p2.Nreal[0] = 48; p2.Nreal[1] = 48; p2.Nreal[2] = 32; p2.Nreal[3] = 32;
  p2.scale[0] = PI_F; p2.scale[1] = PI_F; p2.scale[2] = 0.9f; p2.scale[3] = 0.9f;
  p2.PhiQ = PhiQ; p2.PhiK = PhiK; p2.PhiKT = PhiKT;
  gemm2_phasor<<<dim3(64), 256, 0, stream>>>(p2);

  // 3) fused scan (kv recompute + retrieve)
  scan_fused<<<dim3(64, 2), 256, 0, stream>>>((const ushort*)PhiQ, (const ushort*)PhiK,
                                              (const ushort*)PhiKT, VT, r);

  // 4) LayerNorm + out projection + residual
  out_ln_gemm<<<dim3(64, 4), 256, 0, stream>>>(r, ln_g, ln_b, out_w, out_b, x,
                                               (float*)d_out);
}

// Round 6
// 172.789 us; speedup vs baseline: 1.1419x; 1.1419x over previous
//
#include <hip/hip_runtime.h>
#include <math.h>

// ProductManifoldPhasorBlock — R6: R4 structure (best: 177µs) minus cast and
// layernorm dispatches (both folded into proven R5 kernels). 7 dispatches:
//  1) gemm1       : 5x (MLP1 GELU -> h bf16) + (V proj -> VT bf16), fp32 in-kernel cast
//  2) gemm2f      : 4x MLP2 (tanh*scale -> fp32 angles), z-parallel grid
//  3) phasor_t    : phasors -> PhiQ/PhiK + PhiKT transpose
//  4) kv_chunk    : per-chunk KV sums (MFMA) -> P fp32
//  5) prefix_scan : exclusive chunk prefix, fp32 carry -> bf16 SpreB
//  6) retrieve    : PhiQ@Spre^T + tril(PhiQ@PhiK^T)@V (MFMA) -> r fp32
//  7) out_ln_gemm : LayerNorm in A-staging + out proj + residual -> d_out
// Model: dur ≈ ~150µs harness floor + kernel_sum; this targets kernel_sum.

#define Bn 4
#define Ln 1024
#define BLn 4096

typedef __attribute__((ext_vector_type(8))) short bf16x8;
typedef __attribute__((ext_vector_type(4))) float f32x4;

__device__ inline ushort f2bf(float f) {
  union { float f; uint u; } x; x.f = f;
  uint r = x.u + 0x7fffu + ((x.u >> 16) & 1u);
  return (ushort)(r >> 16);
}
__device__ inline uint pk2(float a, float b) {
  return (uint)f2bf(a) | ((uint)f2bf(b) << 16);
}

// --------------------------------------------------- gemm1 (cast + MFMA)
// act 1: GELU -> bf16 Y[4096][256]; act 4: bf16 transposed -> VT[256][4096]
struct G1Prob { const float* X; const float* W; const float* bias; void* Y; int act; };
struct G1Args { G1Prob p[5]; };

__global__ __launch_bounds__(256) void gemm1(G1Args args) {
  const G1Prob p = args.p[blockIdx.z];
  __shared__ ushort As[64 * 40];
  __shared__ ushort Bs[64 * 40];
  const int tid = threadIdx.x;
  const int m0 = blockIdx.x * 64, n0 = blockIdx.y * 64;
  const int lane = tid & 63, wave = tid >> 6;
  const int wr = wave >> 1, wc = wave & 1;
  const int fr = lane & 15, quad = lane >> 4;
  f32x4 acc[2][2];
#pragma unroll
  for (int i = 0; i < 2; i++)
#pragma unroll
    for (int j = 0; j < 2; j++) acc[i][j] = (f32x4){0.f, 0.f, 0.f, 0.f};

  const int srow = tid >> 2, sch = (tid & 3) * 8;
  for (int k0 = 0; k0 < 256; k0 += 32) {
    float4 a0 = *(const float4*)(p.X + (size_t)(m0 + srow) * 256 + k0 + sch);
    float4 a1 = *(const float4*)(p.X + (size_t)(m0 + srow) * 256 + k0 + sch + 4);
    float4 b0 = *(const float4*)(p.W + (size_t)(n0 + srow) * 256 + k0 + sch);
    float4 b1 = *(const float4*)(p.W + (size_t)(n0 + srow) * 256 + k0 + sch + 4);
    uint4 pa = { pk2(a0.x, a0.y), pk2(a0.z, a0.w), pk2(a1.x, a1.y), pk2(a1.z, a1.w) };
    uint4 pb = { pk2(b0.x, b0.y), pk2(b0.z, b0.w), pk2(b1.x, b1.y), pk2(b1.z, b1.w) };
    *(uint4*)&As[srow * 40 + sch] = pa;
    *(uint4*)&Bs[srow * 40 + sch] = pb;
    __syncthreads();
    bf16x8 fa0 = *(const bf16x8*)&As[(wr * 32 + fr) * 40 + quad * 8];
    bf16x8 fa1 = *(const bf16x8*)&As[(wr * 32 + 16 + fr) * 40 + quad * 8];
    bf16x8 fb0 = *(const bf16x8*)&Bs[(wc * 32 + fr) * 40 + quad * 8];
    bf16x8 fb1 = *(const bf16x8*)&Bs[(wc * 32 + 16 + fr) * 40 + quad * 8];
    acc[0][0] = __builtin_amdgcn_mfma_f32_16x16x32_bf16(fa0, fb0, acc[0][0], 0, 0, 0);
    acc[0][1] = __builtin_amdgcn_mfma_f32_16x16x32_bf16(fa0, fb1, acc[0][1], 0, 0, 0);
    acc[1][0] = __builtin_amdgcn_mfma_f32_16x16x32_bf16(fa1, fb0, acc[1][0], 0, 0, 0);
    acc[1][1] = __builtin_amdgcn_mfma_f32_16x16x32_bf16(fa1, fb1, acc[1][1], 0, 0, 0);
    __syncthreads();
  }
#pragma unroll
  for (int i = 0; i < 2; i++)
#pragma unroll
    for (int j = 0; j < 2; j++) {
      int col = n0 + wc * 32 + j * 16 + fr;
      float bv = p.bias[col];
      if (p.act == 4) {
        int rowg0 = m0 + wr * 32 + i * 16 + quad * 4;
        ushort4 st;
        st.x = f2bf(acc[i][j][0] + bv);
        st.y = f2bf(acc[i][j][1] + bv);
        st.z = f2bf(acc[i][j][2] + bv);
        st.w = f2bf(acc[i][j][3] + bv);
        *(ushort4*)((ushort*)p.Y + (size_t)col * 4096 + rowg0) = st;
      } else {
#pragma unroll
        for (int r = 0; r < 4; r++) {
          int rowg = m0 + wr * 32 + i * 16 + quad * 4 + r;
          float o = acc[i][j][r] + bv;
          o = 0.5f * o * (1.0f + erff(o * 0.70710678118654752f));
          ((ushort*)p.Y)[(size_t)rowg * 256 + col] = f2bf(o);
        }
      }
    }
}

// ------------------------------------------- gemm2f (bf16 X, fp32 W cast)
// Y[4096][64] = tanh(X @ W^T + b) * scale; z-parallel 4 problems, N=64 padded.
struct G2Prob { const ushort* X; const float* W; const float* bias; float* Y;
                int Nreal; float scale; };
struct G2Args { G2Prob p[4]; };

__global__ __launch_bounds__(256) void gemm2f(G2Args args) {
  const G2Prob p = args.p[blockIdx.z];
  __shared__ ushort As[64 * 40];
  __shared__ ushort Bs[64 * 40];
  const int tid = threadIdx.x;
  const int m0 = blockIdx.x * 64;
  const int lane = tid & 63, wave = tid >> 6;
  const int wr = wave >> 1, wc = wave & 1;
  const int fr = lane & 15, quad = lane >> 4;
  f32x4 acc[2][2];
#pragma unroll
  for (int i = 0; i < 2; i++)
#pragma unroll
    for (int j = 0; j < 2; j++) acc[i][j] = (f32x4){0.f, 0.f, 0.f, 0.f};

  const int srow = tid >> 2, sch = (tid & 3) * 8;
  for (int k0 = 0; k0 < 256; k0 += 32) {
    uint4 pa = *(const uint4*)(p.X + (size_t)(m0 + srow) * 256 + k0 + sch);
    float4 b0 = {0.f,0.f,0.f,0.f}, b1 = {0.f,0.f,0.f,0.f};
    if (srow < p.Nreal) {
      b0 = *(const float4*)(p.W + (size_t)srow * 256 + k0 + sch);
      b1 = *(const float4*)(p.W + (size_t)srow * 256 + k0 + sch + 4);
    }
    uint4 pb = { pk2(b0.x, b0.y), pk2(b0.z, b0.w), pk2(b1.x, b1.y), pk2(b1.z, b1.w) };
    *(uint4*)&As[srow * 40 + sch] = pa;
    *(uint4*)&Bs[srow * 40 + sch] = pb;
    __syncthreads();
    bf16x8 fa0 = *(const bf16x8*)&As[(wr * 32 + fr) * 40 + quad * 8];
    bf16x8 fa1 = *(const bf16x8*)&As[(wr * 32 + 16 + fr) * 40 + quad * 8];
    bf16x8 fb0 = *(const bf16x8*)&Bs[(wc * 32 + fr) * 40 + quad * 8];
    bf16x8 fb1 = *(const bf16x8*)&Bs[(wc * 32 + 16 + fr) * 40 + quad * 8];
    acc[0][0] = __builtin_amdgcn_mfma_f32_16x16x32_bf16(fa0, fb0, acc[0][0], 0, 0, 0);
    acc[0][1] = __builtin_amdgcn_mfma_f32_16x16x32_bf16(fa0, fb1, acc[0][1], 0, 0, 0);
    acc[1][0] = __builtin_amdgcn_mfma_f32_16x16x32_bf16(fa1, fb0, acc[1][0], 0, 0, 0);
    acc[1][1] = __builtin_amdgcn_mfma_f32_16x16x32_bf16(fa1, fb1, acc[1][1], 0, 0, 0);
    __syncthreads();
  }
#pragma unroll
  for (int i = 0; i < 2; i++)
#pragma unroll
    for (int j = 0; j < 2; j++) {
      int col = wc * 32 + j * 16 + fr;
      float bv = (col < p.Nreal) ? p.bias[col] : 0.f;
#pragma unroll
      for (int r = 0; r < 4; r++) {
        int row = m0 + wr * 32 + i * 16 + quad * 4 + r;
        p.Y[(size_t)row * 64 + col] = tanhf(acc[i][j][r] + bv) * p.scale;
      }
    }
}

// ----------------------------------------------------------------- phasors
// Emit PhiQ/PhiK [BL][64] packed bf16 pairs and PhiKT [B][128][512] packed.
__global__ __launch_bounds__(256) void phasor_t(const float* kp, const float* qp,
                                                const float* kh, const float* qh,
                                                uint* PhiQ, uint* PhiK, uint* PhiKT) {
  __shared__ ushort LK[64][130];
  const int t = threadIdx.x;
  const int row0 = blockIdx.x * 64;
  const int b = row0 >> 10;
  const int lb0 = row0 & 1023;
#pragma unroll
  for (int it = 0; it < 16; it++) {
    int idx = t + it * 256;            // 64 rows x 64 k
    int k = idx & 63, rl = idx >> 6;
    int row = row0 + rl;
    float kre, kim, qre, qim;
    if (k < 48) {
      float ka = kp[row * 64 + k], qa = qp[row * 64 + k];
      __sincosf(ka, &kim, &kre);
      __sincosf(qa, &qim, &qre);
    } else {
      int j2 = (k - 48) * 2;
      float av = kh[row * 64 + j2], bv = kh[row * 64 + j2 + 1];
      float rr = sqrtf(av * av + bv * bv);
      if (rr > 0.f) { float inv = (1.0f - rr) / rr; kre = av * inv; kim = bv * inv; }
      else          { kre = 1.0f; kim = 0.0f; }
      av = qh[row * 64 + j2]; bv = qh[row * 64 + j2 + 1];
      rr = sqrtf(av * av + bv * bv);
      if (rr > 0.f) { float inv = (1.0f - rr) / rr; qre = av * inv; qim = bv * inv; }
      else          { qre = 1.0f; qim = 0.0f; }
    }
    uint pk = pk2(kre, kim);
    uint pq = pk2(qre, qim);
    PhiK[(size_t)row * 64 + k] = pk;
    PhiQ[(size_t)row * 64 + k] = pq;
    *(uint*)&LK[rl][2 * k] = pk;
  }
  __syncthreads();
#pragma unroll
  for (int it = 0; it < 16; it++) {    // 128 k2-rows x 32 l-pairs = 4096
    int idx = t + it * 256;
    int k2 = idx >> 5, lp = idx & 31;
    uint v = (uint)LK[lp * 2][k2] | ((uint)LK[lp * 2 + 1][k2] << 16);
    PhiKT[(size_t)b * 65536 + k2 * 512 + (lb0 >> 1) + lp] = v;
  }
}

// -------------------------------------------------------------- kv chunks
// P[b,c][d 256][k2 128] = sum_{l in chunk} V[l][d] * PhiK[l][k2]; grid (64, 2).
__global__ __launch_bounds__(256) void kv_chunk(const ushort* VT, const ushort* PhiKT,
                                                float* P) {
  const int bc = blockIdx.x;
  const int b = bc >> 4, c = bc & 15;
  const int d0 = blockIdx.y * 128;
  const int tid = threadIdx.x, lane = tid & 63, wave = tid >> 6;
  const int wr = wave >> 1, wc = wave & 1;
  const int fr = lane & 15, quad = lane >> 4;
  const int colb = b * 1024 + c * 64;
  f32x4 acc[4][4];
#pragma unroll
  for (int i = 0; i < 4; i++)
#pragma unroll
    for (int j = 0; j < 4; j++) acc[i][j] = (f32x4){0.f, 0.f, 0.f, 0.f};
#pragma unroll
  for (int kk = 0; kk < 2; kk++) {
    bf16x8 a[4], bb[4];
#pragma unroll
    for (int i = 0; i < 4; i++)
      a[i] = *(const bf16x8*)(VT + (size_t)(d0 + wr * 64 + i * 16 + fr) * 4096 + colb + kk * 32 + quad * 8);
#pragma unroll
    for (int j = 0; j < 4; j++)
      bb[j] = *(const bf16x8*)(PhiKT + (size_t)b * 131072 + (size_t)(wc * 64 + j * 16 + fr) * 1024 + c * 64 + kk * 32 + quad * 8);
#pragma unroll
    for (int i = 0; i < 4; i++)
#pragma unroll
      for (int j = 0; j < 4; j++)
        acc[i][j] = __builtin_amdgcn_mfma_f32_16x16x32_bf16(a[i], bb[j], acc[i][j], 0, 0, 0);
  }
#pragma unroll
  for (int i = 0; i < 4; i++)
#pragma unroll
    for (int j = 0; j < 4; j++)
#pragma unroll
      for (int r = 0; r < 4; r++) {
        int d = d0 + wr * 64 + i * 16 + quad * 4 + r;
        int k2 = wc * 64 + j * 16 + fr;
        P[((size_t)bc * 256 + d) * 128 + k2] = acc[i][j][r];
      }
}

// ----------------------------------------------------------------- prefix
__global__ void prefix_scan(const float* P, ushort* SpreB) {
  int gid = blockIdx.x * 256 + threadIdx.x;   // 4*256*128 = 131072
  int b = gid >> 15, dk = gid & 32767;
  size_t idx = (size_t)b * 16 * 32768 + dk;
  float run = 0.f;
#pragma unroll 4
  for (int c = 0; c < 16; c++) {
    SpreB[idx] = f2bf(run);
    run += P[idx];
    idx += 32768;
  }
}

// --------------------------------------------------------------- retrieve
// O = PhiQ @ SpreB^T + tril(PhiQ @ PhiK^T) @ V, scaled; grid (64, 2), 4 waves.
__global__ __launch_bounds__(256) void retrieve(const ushort* PhiQ, const ushort* PhiK,
                                                const ushort* VT, const ushort* SpreB,
                                                float* R) {
  __shared__ ushort Sl[64 * 72];
  const int bc = blockIdx.x;
  const int b = bc >> 4, c = bc & 15;
  const int d0 = blockIdx.y * 128;
  const int tid = threadIdx.x, lane = tid & 63, wy = tid >> 6;
  const int fr = lane & 15, quad = lane >> 4;
  const int g0 = b * 1024 + c * 64;
  bf16x8 a[4][4];
#pragma unroll
  for (int i = 0; i < 4; i++)
#pragma unroll
    for (int kk = 0; kk < 4; kk++)
      a[i][kk] = *(const bf16x8*)(PhiQ + (size_t)(g0 + i * 16 + fr) * 128 + kk * 32 + quad * 8);

  f32x4 acc[4][2];
#pragma unroll
  for (int i = 0; i < 4; i++)
#pragma unroll
    for (int j = 0; j < 2; j++) acc[i][j] = (f32x4){0.f, 0.f, 0.f, 0.f};

  // inter-chunk: PhiQ @ SpreB^T
#pragma unroll
  for (int kk = 0; kk < 4; kk++) {
    bf16x8 bb[2];
#pragma unroll
    for (int j = 0; j < 2; j++)
      bb[j] = *(const bf16x8*)(SpreB + ((size_t)bc * 256 + d0 + wy * 32 + j * 16 + fr) * 128 + kk * 32 + quad * 8);
#pragma unroll
    for (int i = 0; i < 4; i++)
#pragma unroll
      for (int j = 0; j < 2; j++)
        acc[i][j] = __builtin_amdgcn_mfma_f32_16x16x32_bf16(a[i][kk], bb[j], acc[i][j], 0, 0, 0);
  }

  // intra-chunk scores: wave wy computes 16-col strip of S (64x64)
  f32x4 sacc[4];
#pragma unroll
  for (int i = 0; i < 4; i++) sacc[i] = (f32x4){0.f, 0.f, 0.f, 0.f};
#pragma unroll
  for (int kk = 0; kk < 4; kk++) {
    bf16x8 bs = *(const bf16x8*)(PhiK + (size_t)(g0 + wy * 16 + fr) * 128 + kk * 32 + quad * 8);
#pragma unroll
    for (int i = 0; i < 4; i++)
      sacc[i] = __builtin_amdgcn_mfma_f32_16x16x32_bf16(a[i][kk], bs, sacc[i], 0, 0, 0);
  }
#pragma unroll
  for (int i = 0; i < 4; i++)
#pragma unroll
    for (int r = 0; r < 4; r++) {
      int row = i * 16 + quad * 4 + r;
      int col = wy * 16 + fr;
      Sl[row * 72 + col] = (col <= row) ? f2bf(sacc[i][r]) : (ushort)0;
    }
  __syncthreads();

  // intra-chunk PV: tril(S) @ V
#pragma unroll
  for (int kk = 0; kk < 2; kk++) {
    bf16x8 as[4], bv[2];
#pragma unroll
    for (int i = 0; i < 4; i++)
      as[i] = *(const bf16x8*)&Sl[(i * 16 + fr) * 72 + kk * 32 + quad * 8];
#pragma unroll
    for (int j = 0; j < 2; j++)
      bv[j] = *(const bf16x8*)(VT + (size_t)(d0 + wy * 32 + j * 16 + fr) * 4096 + g0 + kk * 32 + quad * 8);
#pragma unroll
    for (int i = 0; i < 4; i++)
#pragma unroll
      for (int j = 0; j < 2; j++)
        acc[i][j] = __builtin_amdgcn_mfma_f32_16x16x32_bf16(as[i], bv[j], acc[i][j], 0, 0, 0);
  }

#pragma unroll
  for (int i = 0; i < 4; i++)
#pragma unroll
    for (int j = 0; j < 2; j++)
#pragma unroll
      for (int r = 0; r < 4; r++) {
        int row = i * 16 + quad * 4 + r;
        int d = d0 + wy * 32 + j * 16 + fr;
        float scale = rsqrtf((float)((c * 64 + row + 1) * 64));
        R[(size_t)(g0 + row) * 256 + d] = acc[i][j][r] * scale;
      }
}

// ----------------------------------------- LayerNorm + out proj + residual
__global__ __launch_bounds__(256) void out_ln_gemm(const float* r, const float* g,
                                                   const float* bta, const float* W,
                                                   const float* ob, const float* x,
                                                   float* Y) {
  __shared__ ushort A_lds[64 * 272];
  __shared__ ushort Bs[64 * 40];
  __shared__ float gs[256], bs2[256];
  const int tid = threadIdx.x;
  const int m0 = blockIdx.x * 64, n0 = blockIdx.y * 64;
  gs[tid] = g[tid];
  bs2[tid] = bta[tid];

  const int row_l = tid >> 2, seg = (tid & 3) * 64;
  const float* rr = r + (size_t)(m0 + row_l) * 256 + seg;
  float s = 0.f, sq = 0.f;
#pragma unroll
  for (int i = 0; i < 64; i += 4) {
    float4 v = *(const float4*)(rr + i);
    s += v.x + v.y + v.z + v.w;
    sq += v.x * v.x + v.y * v.y + v.z * v.z + v.w * v.w;
  }
  s += __shfl_xor(s, 1); sq += __shfl_xor(sq, 1);
  s += __shfl_xor(s, 2); sq += __shfl_xor(sq, 2);
  float mean = s * (1.0f / 256.0f);
  float var = fmaxf(sq * (1.0f / 256.0f) - mean * mean, 0.f);
  float rstd = rsqrtf(var + 1e-5f);
  __syncthreads();
#pragma unroll
  for (int i = 0; i < 64; i += 4) {
    float4 v = *(const float4*)(rr + i);
    int k = seg + i;
    ushort4 st;
    st.x = f2bf((v.x - mean) * rstd * gs[k + 0] + bs2[k + 0]);
    st.y = f2bf((v.y - mean) * rstd * gs[k + 1] + bs2[k + 1]);
    st.z = f2bf((v.z - mean) * rstd * gs[k + 2] + bs2[k + 2]);
    st.w = f2bf((v.w - mean) * rstd * gs[k + 3] + bs2[k + 3]);
    *(ushort4*)&A_lds[row_l * 272 + k] = st;
  }
  __syncthreads();

  const int lane = tid & 63, wave = tid >> 6;
  const int wr = wave >> 1, wc = wave & 1;
  const int fr = lane & 15, quad = lane >> 4;
  const int srow = tid >> 2, sch = (tid & 3) * 8;
  f32x4 acc[2][2];
#pragma unroll
  for (int i = 0; i < 2; i++)
#pragma unroll
    for (int j = 0; j < 2; j++) acc[i][j] = (f32x4){0.f, 0.f, 0.f, 0.f};
  for (int k0 = 0; k0 < 256; k0 += 32) {
    float4 b0 = *(const float4*)(W + (size_t)(n0 + srow) * 256 + k0 + sch);
    float4 b1 = *(const float4*)(W + (size_t)(n0 + srow) * 256 + k0 + sch + 4);
    uint4 pb = { pk2(b0.x, b0.y), pk2(b0.z, b0.w), pk2(b1.x, b1.y), pk2(b1.z, b1.w) };
    *(uint4*)&Bs[srow * 40 + sch] = pb;
    __syncthreads();
    bf16x8 fa0 = *(const bf16x8*)&A_lds[(wr * 32 + fr) * 272 + k0 + quad * 8];
    bf16x8 fa1 = *(const bf16x8*)&A_lds[(wr * 32 + 16 + fr) * 272 + k0 + quad * 8];
    bf16x8 fb0 = *(const bf16x8*)&Bs[(wc * 32 + fr) * 40 + quad * 8];
    bf16x8 fb1 = *(const bf16x8*)&Bs[(wc * 32 + 16 + fr) * 40 + quad * 8];
    acc[0][0] = __builtin_amdgcn_mfma_f32_16x16x32_bf16(fa0, fb0, acc[0][0], 0, 0, 0);
    acc[0][1] = __builtin_amdgcn_mfma_f32_16x16x32_bf16(fa0, fb1, acc[0][1], 0, 0, 0);
    acc[1][0] = __builtin_amdgcn_mfma_f32_16x16x32_bf16(fa1, fb0, acc[1][0], 0, 0, 0);
    acc[1][1] = __builtin_amdgcn_mfma_f32_16x16x32_bf16(fa1, fb1, acc[1][1], 0, 0, 0);
    __syncthreads();
  }
#pragma unroll
  for (int i = 0; i < 2; i++)
#pragma unroll
    for (int j = 0; j < 2; j++) {
      int col = n0 + wc * 32 + j * 16 + fr;
      float bv = ob[col];
#pragma unroll
      for (int r = 0; r < 4; r++) {
        int rowg = m0 + wr * 32 + i * 16 + quad * 4 + r;
        Y[(size_t)rowg * 256 + col] = acc[i][j][r] + bv + x[(size_t)rowg * 256 + col];
      }
    }
}

// ------------------------------------------------------------------- launch
extern "C" void kernel_launch(void* const* d_in, const int* in_sizes, int n_in,
                              void* d_out, int out_size, void* d_ws, size_t ws_size,
                              hipStream_t stream) {
  const float* x     = (const float*)d_in[0];
  const float* kp_w1 = (const float*)d_in[1];
  const float* kp_b1 = (const float*)d_in[2];
  const float* kp_w2 = (const float*)d_in[3];
  const float* kp_b2 = (const float*)d_in[4];
  const float* qp_w1 = (const float*)d_in[5];
  const float* qp_b1 = (const float*)d_in[6];
  const float* qp_w2 = (const float*)d_in[7];
  const float* qp_b2 = (const float*)d_in[8];
  const float* kh_w1 = (const float*)d_in[9];
  const float* kh_b1 = (const float*)d_in[10];
  const float* kh_w2 = (const float*)d_in[11];
  const float* kh_b2 = (const float*)d_in[12];
  const float* qh_w1 = (const float*)d_in[13];
  const float* qh_b1 = (const float*)d_in[14];
  const float* qh_w2 = (const float*)d_in[15];
  const float* qh_b2 = (const float*)d_in[16];
  const float* v_w   = (const float*)d_in[17];
  const float* v_b   = (const float*)d_in[18];
  const float* ln_g  = (const float*)d_in[19];
  const float* ln_b  = (const float*)d_in[20];
  const float* out_w = (const float*)d_in[21];
  const float* out_b = (const float*)d_in[22];

  char* ws = (char*)d_ws;
  const size_t MiB = 1024 * 1024;
  ushort* h0   = (ushort*)(ws + 0);            // [4096][256] bf16, 2 MiB each
  ushort* h1   = (ushort*)(ws + 2 * MiB);
  ushort* h2   = (ushort*)(ws + 4 * MiB);
  ushort* h3   = (ushort*)(ws + 6 * MiB);
  ushort* VT   = (ushort*)(ws + 8 * MiB);      // [256][4096] bf16, 2 MiB
  uint*   PhiQ = (uint*)(ws + 10 * MiB);       // [4096][64] packed, 1 MiB
  uint*   PhiK = (uint*)(ws + 11 * MiB);       // 1 MiB
  uint*   PhiKT= (uint*)(ws + 12 * MiB);       // [4][128][512], 1 MiB
  float*  kp   = (float*)(ws + 13 * MiB);      // [4096][64] fp32, 1 MiB each
  float*  qp   = (float*)(ws + 14 * MiB);
  float*  kh   = (float*)(ws + 15 * MiB);
  float*  qh   = (float*)(ws + 16 * MiB);
  float*  P    = (float*)(ws + 17 * MiB);      // [64][256][128] fp32, 8 MiB
  ushort* SpreB= (ushort*)(ws + 25 * MiB);     // bf16, 4 MiB
  float*  r    = (float*)(ws + 29 * MiB);      // [4096][256] fp32, 4 MiB

  // 1) first layers + V projection (fp32 inputs, in-kernel cast)
  G1Args g1;
  g1.p[0] = { x, kp_w1, kp_b1, h0, 1 };
  g1.p[1] = { x, qp_w1, qp_b1, h1, 1 };
  g1.p[2] = { x, kh_w1, kh_b1, h2, 1 };
  g1.p[3] = { x, qh_w1, qh_b1, h3, 1 };
  g1.p[4] = { x, v_w,   v_b,   VT, 4 };
  gemm1<<<dim3(64, 4, 5), 256, 0, stream>>>(g1);

  // 2) second layers, z-parallel (N=64 padded), tanh*scale -> fp32 angles
  const float PI_F = 3.14159265358979323846f;
  G2Args g2;
  g2.p[0] = { h0, kp_w2, kp_b2, kp, 48, PI_F };
  g2.p[1] = { h1, qp_w2, qp_b2, qp, 48, PI_F };
  g2.p[2] = { h2, kh_w2, kh_b2, kh, 32, 0.9f };
  g2.p[3] = { h3, qh_w2, qh_b2, qh, 32, 0.9f };
  gemm2f<<<dim3(64, 1, 4), 256, 0, stream>>>(g2);

  // 3) phasors -> PhiQ, PhiK, PhiKT
  phasor_t<<<dim3(64), 256, 0, stream>>>(kp, qp, kh, qh, PhiQ, PhiK, PhiKT);

  // 4) per-chunk KV sums (MFMA)
  kv_chunk<<<dim3(64, 2), 256, 0, stream>>>(VT, (const ushort*)PhiKT, P);

  // 5) exclusive prefix over chunks -> bf16
  prefix_scan<<<dim3(512), 256, 0, stream>>>(P, SpreB);

  // 6) retrieve (MFMA)
  retrieve<<<dim3(64, 2), 256, 0, stream>>>((const ushort*)PhiQ, (const ushort*)PhiK,
                                            VT, SpreB, r);

  // 7) LayerNorm + out projection + residual
  out_ln_gemm<<<dim3(64, 4), 256, 0, stream>>>(r, ln_g, ln_b, out_w, out_b, x,
                                               (float*)d_out);
}